// Round 1
// baseline (981.307 us; speedup 1.0000x reference)
//
#include <hip/hip_runtime.h>
#include <hip/hip_bf16.h>

#define S_    2048
#define D_    1024
#define H_    16
#define HD_   64
#define NB_   4
#define SCALE 0.125f

using bf16x8 = __attribute__((ext_vector_type(8))) short;
using f32x4  = __attribute__((ext_vector_type(4))) float;

static __device__ __forceinline__ short f2bf(float f) {
  unsigned u = __builtin_bit_cast(unsigned, f);
  u += 0x7fffu + ((u >> 16) & 1u);        // RNE
  return (short)(u >> 16);
}

// ---------------- cast f32 -> bf16 (n multiple of 8) ----------------
__global__ __launch_bounds__(256) void cast_kernel(const float* __restrict__ src,
                                                   short* __restrict__ dst, int n8) {
  int i = blockIdx.x * 256 + threadIdx.x;
  if (i >= n8) return;
  f32x4 a = reinterpret_cast<const f32x4*>(src)[2 * i];
  f32x4 b = reinterpret_cast<const f32x4*>(src)[2 * i + 1];
  bf16x8 o;
  o[0] = f2bf(a[0]); o[1] = f2bf(a[1]); o[2] = f2bf(a[2]); o[3] = f2bf(a[3]);
  o[4] = f2bf(b[0]); o[5] = f2bf(b[1]); o[6] = f2bf(b[2]); o[7] = f2bf(b[3]);
  reinterpret_cast<bf16x8*>(dst)[i] = o;
}

// ---------------- Wt[n][k] = (bf16) W[k][n], 1024x1024 ----------------
__global__ __launch_bounds__(256) void transpose_cast_kernel(const float* __restrict__ W,
                                                             short* __restrict__ Wt) {
  __shared__ float tile[32][33];
  int tx = threadIdx.x, ty = threadIdx.y;           // (32, 8)
  int bx = blockIdx.x * 32, by = blockIdx.y * 32;   // bx: n range, by: k range
#pragma unroll
  for (int i = 0; i < 4; ++i) {
    int k = ty + 8 * i;
    tile[k][tx] = W[(size_t)(by + k) * D_ + bx + tx];
  }
  __syncthreads();
#pragma unroll
  for (int i = 0; i < 4; ++i) {
    int n = ty + 8 * i;
    Wt[(size_t)(bx + n) * D_ + by + tx] = f2bf(tile[tx][n]);
  }
}

// ---------------- GEMM: out = A[8192x1024] @ Bt^T + bias ----------------
// A bf16 row-major [8192][1024]; Bt bf16 [N][K] = W^T.
// MODE 0: out bf16 [B,H,S,HD]; MODE 1: out bf16 [B,H,HD,S]; MODE 2: out f32 [8192][1024]
template <int MODE>
__global__ __launch_bounds__(256) void proj_gemm(const short* __restrict__ A,
                                                 const short* __restrict__ Bt,
                                                 const float* __restrict__ bias,
                                                 void* __restrict__ outp) {
  __shared__ short As[128 * 40];
  __shared__ short Bs[128 * 40];
  const int t = threadIdx.x;
  const int w = t >> 6, l = t & 63, lr = l & 15, lg = l >> 4;
  const int rb = blockIdx.x, cb = blockIdx.y;
  const int wr = w >> 1, wc = w & 1;
  const f32x4 fz = {0.f, 0.f, 0.f, 0.f};
  f32x4 acc[4][4];
#pragma unroll
  for (int mi = 0; mi < 4; ++mi)
#pragma unroll
    for (int ni = 0; ni < 4; ++ni) acc[mi][ni] = fz;

  const int srow = t >> 2, sc8 = (t & 3) * 8;
  for (int k0 = 0; k0 < D_; k0 += 32) {
    __syncthreads();
#pragma unroll
    for (int i = 0; i < 2; ++i) {
      int r = srow + i * 64;
      *reinterpret_cast<bf16x8*>(&As[r * 40 + sc8]) =
          *reinterpret_cast<const bf16x8*>(&A[(size_t)(rb * 128 + r) * D_ + k0 + sc8]);
      *reinterpret_cast<bf16x8*>(&Bs[r * 40 + sc8]) =
          *reinterpret_cast<const bf16x8*>(&Bt[(size_t)(cb * 128 + r) * D_ + k0 + sc8]);
    }
    __syncthreads();
    bf16x8 af[4], bfr[4];
#pragma unroll
    for (int mi = 0; mi < 4; ++mi)
      af[mi] = *reinterpret_cast<bf16x8*>(&As[(wr * 64 + mi * 16 + lr) * 40 + 8 * lg]);
#pragma unroll
    for (int ni = 0; ni < 4; ++ni)
      bfr[ni] = *reinterpret_cast<bf16x8*>(&Bs[(wc * 64 + ni * 16 + lr) * 40 + 8 * lg]);
#pragma unroll
    for (int mi = 0; mi < 4; ++mi)
#pragma unroll
      for (int ni = 0; ni < 4; ++ni)
        acc[mi][ni] = __builtin_amdgcn_mfma_f32_16x16x32_bf16(af[mi], bfr[ni], acc[mi][ni], 0, 0, 0);
  }

#pragma unroll
  for (int mi = 0; mi < 4; ++mi) {
#pragma unroll
    for (int ni = 0; ni < 4; ++ni) {
#pragma unroll
      for (int j = 0; j < 4; ++j) {
        int rr = rb * 128 + wr * 64 + mi * 16 + 4 * lg + j;
        int cc = cb * 128 + wc * 64 + ni * 16 + lr;
        float v = acc[mi][ni][j] + bias[cc];
        int b = rr >> 11, s = rr & 2047, h = cc >> 6, d = cc & 63;
        if (MODE == 0) {
          ((short*)outp)[(((size_t)(b * H_ + h)) * S_ + s) * HD_ + d] = f2bf(v);
        } else if (MODE == 1) {
          ((short*)outp)[(((size_t)(b * H_ + h)) * HD_ + d) * S_ + s] = f2bf(v);
        } else {
          ((float*)outp)[(size_t)rr * D_ + cc] = v;
        }
      }
    }
  }
}

// ---------------- fused attention ----------------
// Q,K bf16 [B,H,S,HD]; Vt bf16 [B,H,HD,S]; mask int32 [B,S,S] (1 = masked)
// writes attn f32 [B,H,S,S] and ctx bf16 [B*S][H*HD]
__global__ __launch_bounds__(256) void attn_kernel(const short* __restrict__ Q,
                                                   const short* __restrict__ K,
                                                   const short* __restrict__ Vt,
                                                   const int* __restrict__ mask,
                                                   float* __restrict__ attn_out,
                                                   short* __restrict__ ctx) {
  __shared__ short Qs[64 * 72];
  __shared__ short Ks[64 * 72];
  __shared__ short Vs[64 * 72];
  __shared__ short Ps[4 * 16 * 72];
  const int t = threadIdx.x;
  const int w = t >> 6, l = t & 63, lr = l & 15, lg = l >> 4;
  const int qt = blockIdx.x, bh = blockIdx.y;
  const int b = bh >> 4, h = bh & 15;
  const int qbase = qt * 64;

  const short* Qg = Q + ((size_t)bh * S_ + qbase) * HD_;
  const short* Kg = K + (size_t)bh * S_ * HD_;
  const short* Vg = Vt + (size_t)bh * HD_ * S_;
  const int* mb = mask + (size_t)b * S_ * S_;

  const int srow = t >> 3, sc8 = (t & 7) * 8;
  // stage Q tile
#pragma unroll
  for (int i = 0; i < 2; ++i) {
    int r = srow + i * 32;
    *reinterpret_cast<bf16x8*>(&Qs[r * 72 + sc8]) =
        *reinterpret_cast<const bf16x8*>(&Qg[(size_t)r * HD_ + sc8]);
  }
  __syncthreads();
  bf16x8 qf[2];
#pragma unroll
  for (int c = 0; c < 2; ++c)
    qf[c] = *reinterpret_cast<bf16x8*>(&Qs[(16 * w + lr) * 72 + 32 * c + 8 * lg]);

  const int q0 = qbase + 16 * w + 4 * lg;  // + j

  float m[4], ll[4];
#pragma unroll
  for (int j = 0; j < 4; ++j) { m[j] = -3e38f; ll[j] = 0.0f; }

  const f32x4 fz = {0.f, 0.f, 0.f, 0.f};

  // ---------- pass 1: row max + sum ----------
  for (int kt = 0; kt < S_ / 64; ++kt) {
    __syncthreads();
#pragma unroll
    for (int i = 0; i < 2; ++i) {
      int r = srow + i * 32;
      *reinterpret_cast<bf16x8*>(&Ks[r * 72 + sc8]) =
          *reinterpret_cast<const bf16x8*>(&Kg[(size_t)(kt * 64 + r) * HD_ + sc8]);
    }
    __syncthreads();
    f32x4 sc[4];
#pragma unroll
    for (int nf = 0; nf < 4; ++nf) {
      f32x4 a = fz;
#pragma unroll
      for (int c = 0; c < 2; ++c) {
        bf16x8 kf = *reinterpret_cast<bf16x8*>(&Ks[(16 * nf + lr) * 72 + 32 * c + 8 * lg]);
        a = __builtin_amdgcn_mfma_f32_16x16x32_bf16(qf[c], kf, a, 0, 0, 0);
      }
      sc[nf] = a;
    }
#pragma unroll
    for (int j = 0; j < 4; ++j) {
      const int* mrow = mb + (size_t)(q0 + j) * S_ + kt * 64 + lr;
      float v[4];
#pragma unroll
      for (int nf = 0; nf < 4; ++nf) {
        float sv = sc[nf][j] * SCALE;
        if (mrow[nf * 16]) sv = -1e9f;
        v[nf] = sv;
      }
      float vm = fmaxf(fmaxf(v[0], v[1]), fmaxf(v[2], v[3]));
      float nm = fmaxf(m[j], vm);
      float sum = __expf(v[0] - nm) + __expf(v[1] - nm) + __expf(v[2] - nm) + __expf(v[3] - nm);
      ll[j] = ll[j] * __expf(m[j] - nm) + sum;
      m[j] = nm;
    }
  }
  // merge partials across the 16 lanes that share rows
#pragma unroll
  for (int off = 1; off < 16; off <<= 1) {
#pragma unroll
    for (int j = 0; j < 4; ++j) {
      float mo = __shfl_xor(m[j], off, 64);
      float lo = __shfl_xor(ll[j], off, 64);
      float nm = fmaxf(m[j], mo);
      ll[j] = ll[j] * __expf(m[j] - nm) + lo * __expf(mo - nm);
      m[j] = nm;
    }
  }
  float rl[4];
#pragma unroll
  for (int j = 0; j < 4; ++j) rl[j] = ll[j] > 0.0f ? 1.0f / ll[j] : 0.0f;

  // ---------- pass 2: write attn, accumulate ctx ----------
  f32x4 ctxa[4];
#pragma unroll
  for (int df = 0; df < 4; ++df) ctxa[df] = fz;
  short* Pw = &Ps[w * 16 * 72];

  for (int kt = 0; kt < S_ / 64; ++kt) {
    __syncthreads();
#pragma unroll
    for (int i = 0; i < 2; ++i) {
      int r = srow + i * 32;
      *reinterpret_cast<bf16x8*>(&Ks[r * 72 + sc8]) =
          *reinterpret_cast<const bf16x8*>(&Kg[(size_t)(kt * 64 + r) * HD_ + sc8]);
      *reinterpret_cast<bf16x8*>(&Vs[r * 72 + sc8]) =
          *reinterpret_cast<const bf16x8*>(&Vg[(size_t)r * S_ + kt * 64 + sc8]);
    }
    __syncthreads();
    f32x4 sc[4];
#pragma unroll
    for (int nf = 0; nf < 4; ++nf) {
      f32x4 a = fz;
#pragma unroll
      for (int c = 0; c < 2; ++c) {
        bf16x8 kf = *reinterpret_cast<bf16x8*>(&Ks[(16 * nf + lr) * 72 + 32 * c + 8 * lg]);
        a = __builtin_amdgcn_mfma_f32_16x16x32_bf16(qf[c], kf, a, 0, 0, 0);
      }
      sc[nf] = a;
    }
#pragma unroll
    for (int j = 0; j < 4; ++j) {
      const int* mrow = mb + (size_t)(q0 + j) * S_ + kt * 64 + lr;
      float* arow = attn_out + ((size_t)bh * S_ + (q0 + j)) * S_ + kt * 64 + lr;
#pragma unroll
      for (int nf = 0; nf < 4; ++nf) {
        float sv = sc[nf][j] * SCALE;
        if (mrow[nf * 16]) sv = -1e9f;
        float p = __expf(sv - m[j]) * rl[j];
        arow[nf * 16] = p;
        Pw[(4 * lg + j) * 72 + nf * 16 + lr] = f2bf(p);
      }
    }
    // per-wave LDS W->R ordering (cross-lane, same wave): drain lgkm
    asm volatile("s_waitcnt lgkmcnt(0)" ::: "memory");
    bf16x8 pf[2];
#pragma unroll
    for (int c = 0; c < 2; ++c)
      pf[c] = *reinterpret_cast<bf16x8*>(&Pw[lr * 72 + 32 * c + 8 * lg]);
#pragma unroll
    for (int df = 0; df < 4; ++df) {
#pragma unroll
      for (int c = 0; c < 2; ++c) {
        bf16x8 vf = *reinterpret_cast<bf16x8*>(&Vs[(16 * df + lr) * 72 + 32 * c + 8 * lg]);
        ctxa[df] = __builtin_amdgcn_mfma_f32_16x16x32_bf16(pf[c], vf, ctxa[df], 0, 0, 0);
      }
    }
  }

  // ctx write: [b*S + q][h*64 + d], bf16
#pragma unroll
  for (int df = 0; df < 4; ++df)
#pragma unroll
    for (int j = 0; j < 4; ++j)
      ctx[((size_t)b * S_ + (q0 + j)) * D_ + h * HD_ + df * 16 + lr] = f2bf(ctxa[df][j]);
}

extern "C" void kernel_launch(void* const* d_in, const int* in_sizes, int n_in,
                              void* d_out, int out_size, void* d_ws, size_t ws_size,
                              hipStream_t stream) {
  const float* query = (const float*)d_in[0];
  const float* key   = (const float*)d_in[1];
  const float* value = (const float*)d_in[2];
  const int*   mask  = (const int*)d_in[3];
  const float* Wq = (const float*)d_in[4];
  const float* bq = (const float*)d_in[5];
  const float* Wk = (const float*)d_in[6];
  const float* bk = (const float*)d_in[7];
  const float* Wv = (const float*)d_in[8];
  const float* bv = (const float*)d_in[9];
  const float* Wo = (const float*)d_in[10];
  const float* bo = (const float*)d_in[11];

  char* ws = (char*)d_ws;
  const size_t BIG = 16777216;  // 8192*1024*2 bytes
  short* Xbuf  = (short*)(ws);
  short* Qbuf  = (short*)(ws + BIG);
  short* Kbuf  = (short*)(ws + 2 * BIG);
  short* Vtbuf = (short*)(ws + 3 * BIG);
  short* Wqt   = (short*)(ws + 4 * BIG);
  short* Wkt   = (short*)(ws + 4 * BIG + 2097152);
  short* Wvt   = (short*)(ws + 4 * BIG + 2 * 2097152);
  short* Wot   = (short*)(ws + 4 * BIG + 3 * 2097152);
  short* ctx   = Xbuf;  // reuse after projections

  float* out0 = (float*)d_out;
  float* attn_out = out0 + (size_t)NB_ * S_ * D_;  // 8388608

  dim3 tcb(32, 8), tcg(32, 32);
  transpose_cast_kernel<<<tcg, tcb, 0, stream>>>(Wq, Wqt);
  transpose_cast_kernel<<<tcg, tcb, 0, stream>>>(Wk, Wkt);
  transpose_cast_kernel<<<tcg, tcb, 0, stream>>>(Wv, Wvt);
  transpose_cast_kernel<<<tcg, tcb, 0, stream>>>(Wo, Wot);

  const int n8 = (NB_ * S_ * D_) / 8;  // 1048576
  dim3 gemm_g(64, 8);

  cast_kernel<<<n8 / 256, 256, 0, stream>>>(query, Xbuf, n8);
  proj_gemm<0><<<gemm_g, 256, 0, stream>>>(Xbuf, Wqt, bq, Qbuf);
  cast_kernel<<<n8 / 256, 256, 0, stream>>>(key, Xbuf, n8);
  proj_gemm<0><<<gemm_g, 256, 0, stream>>>(Xbuf, Wkt, bk, Kbuf);
  cast_kernel<<<n8 / 256, 256, 0, stream>>>(value, Xbuf, n8);
  proj_gemm<1><<<gemm_g, 256, 0, stream>>>(Xbuf, Wvt, bv, Vtbuf);

  attn_kernel<<<dim3(32, 64), 256, 0, stream>>>(Qbuf, Kbuf, Vtbuf, mask, attn_out, ctx);

  proj_gemm<2><<<gemm_g, 256, 0, stream>>>(ctx, Wot, bo, out0);
}